// Round 6
// baseline (572.756 us; speedup 1.0000x reference)
//
#include <hip/hip_runtime.h>
#include <hip/hip_bf16.h>

#define EPSV 1e-12
#define RHASH 0.2

__device__ __forceinline__ int fmod2(double t) {
    // floor then mod 2 with numpy semantics (non-negative result)
    return (int)(((long long)floor(t)) & 1LL);
}

__device__ __forceinline__ void load_row6(const float* base, float* r) {
    float2 a0 = *(const float2*)(base);
    float2 a1 = *(const float2*)(base + 2);
    float2 a2 = *(const float2*)(base + 4);
    r[0] = a0.x; r[1] = a0.y; r[2] = a1.x; r[3] = a1.y; r[4] = a2.x; r[5] = a2.y;
}

// ---------------------------------------------------------------------------
// setup: per-layer kernel hashes kh[], per-cin a-sums, query constants (double)
// dmeta layout: [0..2]=asum1, [3..18]=asum2, [19..38]=asum3, [39]=qc1,[40]=qc2,[41]=qc3
// imeta layout: [0..15]=kh1, [16..35]=kh2, [36..55]=kh3
// (identical to the verified round-2 version)
// ---------------------------------------------------------------------------
__device__ void layer_setup(const float* W, const float* a, double cval,
                            int Co, int Ci, int* kh, double* asum, double* qc,
                            double* s_norm, float* Wbuf, float* abuf)
{
    const int t = threadIdx.x;
    const int D = Ci * 25;
    for (int i = t; i < Co * D; i += 256) Wbuf[i] = W[i];
    for (int i = t; i < D + 5; i += 256) abuf[i] = a[i];
    __syncthreads();
    if (t < Co) {
        double s = 0;
        for (int j = 0; j < D; ++j) { double w = (double)Wbuf[t * D + j]; s += w * w; }
        s_norm[t] = sqrt(s);
    }
    __syncthreads();
    if (t == 0) {
        double mx = 0;
        for (int i = 0; i < Co; ++i) mx = fmax(mx, s_norm[i]);
        s_norm[23] = 1.0 / (mx + EPSV);
    }
    __syncthreads();
    double scale = s_norm[23];
    if (t < Co) {
        double dp = 0;
        for (int j = 0; j < D; ++j) dp += (double)Wbuf[t * D + j] * (double)abuf[j];
        dp *= scale;
        double n = s_norm[t] * scale;
        double p = n * n;                       // n^2, n^4, n^8, n^16, n^32
        for (int m = 0; m < 5; ++m) { dp += p * (double)abuf[D + m]; p *= p; }
        kh[t] = fmod2((dp + cval) / RHASH);
    }
    if (t >= 64 && t < 64 + Ci) {
        int c = t - 64;
        double s = 0;
        for (int j = 0; j < 25; ++j) s += (double)abuf[c * 25 + j];
        asum[c] = s;
    }
    if (t == 128) {
        double s = 0;
        for (int m = 0; m < 5; ++m) s += (double)abuf[D + m];
        *qc = 0.5 * s + cval;
    }
    __syncthreads();
}

__global__ __launch_bounds__(256) void setup_kernel(
    const float* W1, const float* a1, const float* c1,
    const float* W2, const float* a2, const float* c2,
    const float* W3, const float* a3, const float* c3,
    double* dmeta, int* imeta)
{
    __shared__ float Wbuf[10000];
    __shared__ float abuf[512];
    __shared__ double s_norm[24];
    layer_setup(W1, a1, (double)c1[0], 16, 3,  imeta + 0,  dmeta + 0,  dmeta + 39, s_norm, Wbuf, abuf);
    layer_setup(W2, a2, (double)c2[0], 20, 16, imeta + 16, dmeta + 3,  dmeta + 40, s_norm, Wbuf, abuf);
    layer_setup(W3, a3, (double)c3[0], 20, 20, imeta + 36, dmeta + 19, dmeta + 41, s_norm, Wbuf, abuf);
}

// ---------------------------------------------------------------------------
// weight repack:
// Wp1: [ci3][ky5][kx5][co16]                  = 1200 floats
// Wp2: [ci16][ky5][cog4][28] (j=clocal*5+kx)  = 8960 floats
// Wp3: [ci20][ky5][cog4][28]                  = 11200 floats
// ---------------------------------------------------------------------------
__global__ __launch_bounds__(256) void pack_kernel(const float* W1, const float* W2, const float* W3,
                                                   float* Wp1, float* Wp2, float* Wp3)
{
    int i = blockIdx.x * 256 + threadIdx.x;
    if (i < 1200) {
        int co = i & 15, r = i >> 4;           // r = (ci*5+ky)*5+kx
        int kx = r % 5, r2 = r / 5, ky = r2 % 5, ci = r2 / 5;
        Wp1[i] = W1[co * 75 + ci * 25 + ky * 5 + kx];
    } else if (i < 1200 + 8960) {
        int k = i - 1200;
        int j = k % 28, r = k / 28;            // r = (ci*5+ky)*4+cog
        int cog = r % 4, r2 = r / 4, ky = r2 % 5, ci = r2 / 5;
        Wp2[k] = (j < 25) ? W2[(cog * 5 + j / 5) * 400 + ci * 25 + ky * 5 + (j % 5)] : 0.f;
    } else if (i < 1200 + 8960 + 11200) {
        int k = i - 10160;
        int j = k % 28, r = k / 28;
        int cog = r % 4, r2 = r / 4, ky = r2 % 5, ci = r2 / 5;
        Wp3[k] = (j < 25) ? W3[(cog * 5 + j / 5) * 500 + ci * 25 + ky * 5 + (j % 5)] : 0.f;
    }
}

// ---------------------------------------------------------------------------
// conv1: x[B,3,32,32] -> h1[B,16,16,16]; block=sample; thread=pooled pos,
// all 16 co, 2x2 quad in-thread. Rolling row window. Fused qh1/qh2.
// Stride 36 (reverted: padding cannot fix even-bank patterns).
// ---------------------------------------------------------------------------
__global__ __launch_bounds__(256) void conv1_kernel(
    const float* __restrict__ x, const float* __restrict__ Wp1,
    const float* __restrict__ b1, const int* __restrict__ kh1,
    const double* __restrict__ dmeta, float* __restrict__ h1,
    int* __restrict__ qh2)
{
    __shared__ float xs[3][36][36];
    __shared__ float Ws[1200];
    __shared__ double s_red[3];
    __shared__ double s_ch[16][4];

    const int b = blockIdx.x, t = threadIdx.x;
    const int w = t >> 6, ln = t & 63;

    for (int i = t; i < 3 * 36 * 36; i += 256) (&xs[0][0][0])[i] = 0.f;
    for (int i = t; i < 600; i += 256) ((float2*)Ws)[i] = ((const float2*)Wp1)[i];
    __syncthreads();
    const float2* xb2 = (const float2*)(x + (size_t)b * 3072);
    for (int i = t; i < 1536; i += 256) {
        int idx = i * 2, c = idx >> 10, rem = idx & 1023;
        *(float2*)&xs[c][(rem >> 5) + 2][(rem & 31) + 2] = xb2[i];
    }
    __syncthreads();

    // qh1 from x-tile: wave w (w<3) reduces channel w
    if (w < 3) {
        double s = 0;
        for (int j = 0; j < 16; ++j) {
            int i = ln + 64 * j;
            s += (double)xs[w][(i >> 5) + 2][(i & 31) + 2];
        }
        #pragma unroll
        for (int off = 32; off; off >>= 1) s += __shfl_xor(s, off);
        if (ln == 0) s_red[w] = s;
    }
    __syncthreads();
    double dp = 0, nn = 0;
    #pragma unroll
    for (int c = 0; c < 3; ++c) {
        double cm = s_red[c] * (1.0 / 1024.0);
        dp += cm * dmeta[c]; nn += cm * cm;
    }
    const int qh = fmod2((dp / (5.0 * sqrt(nn) + EPSV) + dmeta[39]) / RHASH);

    const int py = t >> 4, px = t & 15;
    const int y0 = 2 * py, x0 = 2 * px;

    float acc[16][4];
    #pragma unroll
    for (int c = 0; c < 16; ++c) {
        float bb = b1[c];
        acc[c][0] = bb; acc[c][1] = bb; acc[c][2] = bb; acc[c][3] = bb;
    }
    #pragma unroll
    for (int ci = 0; ci < 3; ++ci) {
        float cur[6], nxt[6];
        load_row6(&xs[ci][y0][x0], cur);
        load_row6(&xs[ci][y0 + 1][x0], nxt);
        #pragma unroll
        for (int ky = 0; ky < 5; ++ky) {
            const float* wbase = Ws + ((ci * 5 + ky) * 5) * 16;
            #pragma unroll
            for (int kx = 0; kx < 5; ++kx) {
                float wc[16];
                const float4* wp = (const float4*)(wbase + kx * 16);
                *(float4*)&wc[0]  = wp[0];
                *(float4*)&wc[4]  = wp[1];
                *(float4*)&wc[8]  = wp[2];
                *(float4*)&wc[12] = wp[3];
                #pragma unroll
                for (int c = 0; c < 16; ++c) {
                    acc[c][0] = fmaf(wc[c], cur[kx],     acc[c][0]);
                    acc[c][1] = fmaf(wc[c], cur[kx + 1], acc[c][1]);
                    acc[c][2] = fmaf(wc[c], nxt[kx],     acc[c][2]);
                    acc[c][3] = fmaf(wc[c], nxt[kx + 1], acc[c][3]);
                }
            }
            if (ky < 4) {
                #pragma unroll
                for (int j = 0; j < 6; ++j) cur[j] = nxt[j];
                load_row6(&xs[ci][y0 + ky + 2][x0], nxt);
            }
        }
    }

    // store masked pooled output + accumulate per-channel sums for qh2
    float mv[16];
    float* hb = h1 + (size_t)b * 4096 + t;
    #pragma unroll
    for (int c = 0; c < 16; ++c) {
        float m = fmaxf(fmaxf(acc[c][0], acc[c][1]), fmaxf(acc[c][2], acc[c][3]));
        mv[c] = fmaxf(m, 0.f) * ((kh1[c] == qh) ? 1.f : 0.f);
        hb[c * 256] = mv[c];
    }
    #pragma unroll
    for (int c = 0; c < 16; ++c) {
        double s = (double)mv[c];
        #pragma unroll
        for (int off = 32; off; off >>= 1) s += __shfl_xor(s, off);
        if (ln == 0) s_ch[c][w] = s;
    }
    __syncthreads();
    if (t == 0) {
        double dp2 = 0, nn2 = 0;
        #pragma unroll
        for (int c = 0; c < 16; ++c) {
            double cm = (s_ch[c][0] + s_ch[c][1] + s_ch[c][2] + s_ch[c][3]) * (1.0 / 256.0);
            dp2 += cm * dmeta[3 + c]; nn2 += cm * cm;
        }
        qh2[b] = fmod2((dp2 / (5.0 * sqrt(nn2) + EPSV) + dmeta[40]) / RHASH);
    }
}

// ---------------------------------------------------------------------------
// conv2: h1[B,16,16,16] -> h2[B,20,8,8]; block = 2 samples;
// thread = (cog4 x [s2 x py8 x pxp4]): 5 co x TWO 2x2 quads (pooled px=pxp,pxp+4)
// -> 8 outputs/thread; weights amortized 2x vs quad scheme.
// K chunked 4 ci (LDS 12.8 + 8.96 = 21.8KB); stride 20; rolling rows.
// Fused qh3 per sample (half-wave butterflies).
// ---------------------------------------------------------------------------
__global__ __launch_bounds__(256) void conv2_kernel(
    const float* __restrict__ h1, const float* __restrict__ Wp2,
    const float* __restrict__ b2, const int* __restrict__ kh2,
    const int* __restrict__ qh2, const double* __restrict__ dmeta,
    float* __restrict__ h2, int* __restrict__ qh3)
{
    __shared__ float xs[2][4][20][20];
    __shared__ float Ws[2240];           // [ci4][ky5][cog4][28]
    __shared__ double s_ch[2][20];

    const int b0 = blockIdx.x * 2, t = threadIdx.x;
    const int cog = t >> 6, slot = t & 63;
    const int s = slot >> 5, py = (slot >> 2) & 7, pxp = slot & 3;
    const int y0 = 2 * py, x0a = 2 * pxp, x0b = 2 * pxp + 8;

    for (int i = t; i < 3200; i += 256) (&xs[0][0][0][0])[i] = 0.f;

    const int qh = qh2[b0 + s];
    float acc[5][8];
    #pragma unroll
    for (int c = 0; c < 5; ++c) {
        float bb = b2[cog * 5 + c];
        #pragma unroll
        for (int j = 0; j < 8; ++j) acc[c][j] = bb;
    }
    __syncthreads();

    for (int ch = 0; ch < 4; ++ch) {
        for (int i = t; i < 1120; i += 256)
            ((float2*)Ws)[i] = ((const float2*)(Wp2 + ch * 2240))[i];
        for (int i = t; i < 1024; i += 256) {
            int ss = i >> 9, r = i & 511, ci = r >> 7, rr = r & 127, p2 = rr * 2;
            *(float2*)&xs[ss][ci][(p2 >> 4) + 2][(p2 & 15) + 2] =
                ((const float2*)(h1 + (size_t)(b0 + ss) * 4096 + (ch * 4 + ci) * 256))[rr];
        }
        __syncthreads();

        #pragma unroll
        for (int ci = 0; ci < 4; ++ci) {
            float ca[6], na[6], cb[6], nb[6];
            load_row6(&xs[s][ci][y0][x0a], ca);
            load_row6(&xs[s][ci][y0 + 1][x0a], na);
            load_row6(&xs[s][ci][y0][x0b], cb);
            load_row6(&xs[s][ci][y0 + 1][x0b], nb);
            #pragma unroll
            for (int ky = 0; ky < 5; ++ky) {
                float wv[28];
                const float4* wp = (const float4*)&Ws[((ci * 5 + ky) * 4 + cog) * 28];
                *(float4*)&wv[0]  = wp[0];
                *(float4*)&wv[4]  = wp[1];
                *(float4*)&wv[8]  = wp[2];
                *(float4*)&wv[12] = wp[3];
                *(float4*)&wv[16] = wp[4];
                *(float4*)&wv[20] = wp[5];
                *(float4*)&wv[24] = wp[6];
                #pragma unroll
                for (int c = 0; c < 5; ++c) {
                    #pragma unroll
                    for (int kx = 0; kx < 5; ++kx) {
                        float wgt = wv[c * 5 + kx];
                        acc[c][0] = fmaf(wgt, ca[kx],     acc[c][0]);
                        acc[c][1] = fmaf(wgt, ca[kx + 1], acc[c][1]);
                        acc[c][2] = fmaf(wgt, na[kx],     acc[c][2]);
                        acc[c][3] = fmaf(wgt, na[kx + 1], acc[c][3]);
                        acc[c][4] = fmaf(wgt, cb[kx],     acc[c][4]);
                        acc[c][5] = fmaf(wgt, cb[kx + 1], acc[c][5]);
                        acc[c][6] = fmaf(wgt, nb[kx],     acc[c][6]);
                        acc[c][7] = fmaf(wgt, nb[kx + 1], acc[c][7]);
                    }
                }
                if (ky < 4) {
                    #pragma unroll
                    for (int j = 0; j < 6; ++j) { ca[j] = na[j]; cb[j] = nb[j]; }
                    load_row6(&xs[s][ci][y0 + ky + 2][x0a], na);
                    load_row6(&xs[s][ci][y0 + ky + 2][x0b], nb);
                }
            }
        }
        __syncthreads();
    }

    // store 2 pooled outputs per co + fused qh3 (per-sample half-wave reduce)
    float* ob = h2 + (size_t)(b0 + s) * 1280 + py * 8 + pxp;
    double csum[5];
    #pragma unroll
    for (int c = 0; c < 5; ++c) {
        int co = cog * 5 + c;
        float mask = (kh2[co] == qh) ? 1.f : 0.f;
        float mA = fmaxf(fmaxf(acc[c][0], acc[c][1]), fmaxf(acc[c][2], acc[c][3]));
        float mB = fmaxf(fmaxf(acc[c][4], acc[c][5]), fmaxf(acc[c][6], acc[c][7]));
        float vA = fmaxf(mA, 0.f) * mask;
        float vB = fmaxf(mB, 0.f) * mask;
        ob[co * 64]     = vA;
        ob[co * 64 + 4] = vB;
        csum[c] = (double)vA + (double)vB;
    }
    #pragma unroll
    for (int c = 0; c < 5; ++c) {
        double sv = csum[c];
        #pragma unroll
        for (int off = 16; off; off >>= 1) sv += __shfl_xor(sv, off);  // within 32-lane half
        if ((slot & 31) == 0) s_ch[s][cog * 5 + c] = sv;
    }
    __syncthreads();
    if (t < 2) {
        double dp2 = 0, nn2 = 0;
        #pragma unroll
        for (int c = 0; c < 20; ++c) {
            double cm = s_ch[t][c] * (1.0 / 64.0);
            dp2 += cm * dmeta[19 + c]; nn2 += cm * cm;
        }
        qh3[b0 + t] = fmod2((dp2 / (5.0 * sqrt(nn2) + EPSV) + dmeta[41]) / RHASH);
    }
}

// ---------------------------------------------------------------------------
// conv3 + linear: h2[B,20,8,8] -> out[B,10]; block = 4 samples;
// thread = (s4 x cog4 x pos16), 5 co x 2x2 quad; K chunked in 4x5 ci;
// rolling rows; stride 12 (reverted: conflict-free broadcast pattern).
// ---------------------------------------------------------------------------
__global__ __launch_bounds__(256) void conv3_kernel(
    const float* __restrict__ h2, const float* __restrict__ Wp3,
    const float* __restrict__ b3, const int* __restrict__ kh3,
    const int* __restrict__ qh3,
    const float* __restrict__ Wo, const float* __restrict__ bo,
    float* __restrict__ out, int B)
{
    __shared__ float xs[4][5][12][12];
    __shared__ float Ws[2800];           // [ci5][ky5][cog4][28]
    __shared__ float flat[4][320];

    const int b0 = blockIdx.x * 4, t = threadIdx.x;
    const int s = t >> 6, q = t & 63, cog = q >> 4, pos = q & 15;
    const int py = pos >> 2, px = pos & 3;
    const int y0 = 2 * py, x0 = 2 * px;
    const int b = b0 + s;

    for (int i = t; i < 4 * 5 * 144; i += 256) (&xs[0][0][0][0])[i] = 0.f;

    const int qh = (b < B) ? qh3[b] : 0;
    float acc[5][4];
    #pragma unroll
    for (int c = 0; c < 5; ++c) {
        float bb = b3[cog * 5 + c];
        acc[c][0] = bb; acc[c][1] = bb; acc[c][2] = bb; acc[c][3] = bb;
    }
    __syncthreads();

    for (int ch = 0; ch < 4; ++ch) {
        for (int i = t; i < 1400; i += 256)
            ((float2*)Ws)[i] = ((const float2*)(Wp3 + ch * 2800))[i];
        for (int i = t; i < 640; i += 256) {
            int ss = i / 160, r = i - ss * 160, ci = r >> 5, rr = r & 31, p2 = rr * 2;
            if (b0 + ss < B)
                *(float2*)&xs[ss][ci][(p2 >> 3) + 2][(p2 & 7) + 2] =
                    ((const float2*)(h2 + (size_t)(b0 + ss) * 1280 + (ch * 5 + ci) * 64))[rr];
        }
        __syncthreads();

        #pragma unroll
        for (int ci = 0; ci < 5; ++ci) {
            float cur[6], nxt[6];
            load_row6(&xs[s][ci][y0][x0], cur);
            load_row6(&xs[s][ci][y0 + 1][x0], nxt);
            #pragma unroll
            for (int ky = 0; ky < 5; ++ky) {
                float wv[28];
                const float4* wp = (const float4*)&Ws[((ci * 5 + ky) * 4 + cog) * 28];
                *(float4*)&wv[0]  = wp[0];
                *(float4*)&wv[4]  = wp[1];
                *(float4*)&wv[8]  = wp[2];
                *(float4*)&wv[12] = wp[3];
                *(float4*)&wv[16] = wp[4];
                *(float4*)&wv[20] = wp[5];
                *(float4*)&wv[24] = wp[6];
                #pragma unroll
                for (int c = 0; c < 5; ++c) {
                    #pragma unroll
                    for (int kx = 0; kx < 5; ++kx) {
                        float wgt = wv[c * 5 + kx];
                        acc[c][0] = fmaf(wgt, cur[kx],     acc[c][0]);
                        acc[c][1] = fmaf(wgt, cur[kx + 1], acc[c][1]);
                        acc[c][2] = fmaf(wgt, nxt[kx],     acc[c][2]);
                        acc[c][3] = fmaf(wgt, nxt[kx + 1], acc[c][3]);
                    }
                }
                if (ky < 4) {
                    #pragma unroll
                    for (int j = 0; j < 6; ++j) cur[j] = nxt[j];
                    load_row6(&xs[s][ci][y0 + ky + 2][x0], nxt);
                }
            }
        }
        __syncthreads();
    }

    #pragma unroll
    for (int c = 0; c < 5; ++c) {
        int co = cog * 5 + c;
        float m = fmaxf(fmaxf(acc[c][0], acc[c][1]), fmaxf(acc[c][2], acc[c][3]));
        flat[s][co * 16 + pos] = fmaxf(m, 0.f) * ((kh3[co] == qh) ? 1.f : 0.f);
    }
    __syncthreads();

    // linear 320->10 for 4 samples: 40 (s,o) pairs x 4 lanes each
    if (t < 160) {
        const int g = t >> 2, qq = t & 3;
        const int ss = g / 10, o = g - ss * 10;
        float a = 0.f;
        const float* wr = Wo + o * 320;
        for (int k = qq; k < 320; k += 4) a = fmaf(flat[ss][k], wr[k], a);
        a += __shfl_xor(a, 1);
        a += __shfl_xor(a, 2);
        if (qq == 0 && b0 + ss < B) out[(size_t)(b0 + ss) * 10 + o] = a + bo[o];
    }
}

// ---------------------------------------------------------------------------
extern "C" void kernel_launch(void* const* d_in, const int* in_sizes, int n_in,
                              void* d_out, int out_size, void* d_ws, size_t ws_size,
                              hipStream_t stream)
{
    const float* x  = (const float*)d_in[0];
    const float* W1 = (const float*)d_in[1];
    const float* b1 = (const float*)d_in[2];
    const float* a1 = (const float*)d_in[3];
    const float* c1 = (const float*)d_in[4];
    const float* W2 = (const float*)d_in[5];
    const float* b2 = (const float*)d_in[6];
    const float* a2 = (const float*)d_in[7];
    const float* c2 = (const float*)d_in[8];
    const float* W3 = (const float*)d_in[9];
    const float* b3 = (const float*)d_in[10];
    const float* a3 = (const float*)d_in[11];
    const float* c3 = (const float*)d_in[12];
    const float* Wo = (const float*)d_in[13];
    const float* bo = (const float*)d_in[14];
    float* out = (float*)d_out;

    const int B = in_sizes[0] / 3072;   // 4096 (even)

    float* h1  = (float*)d_ws;                       // B*4096 f32
    float* h2  = h1 + (size_t)B * 4096;              // B*1280 f32
    float* Wp1 = h2 + (size_t)B * 1280;              // 1200
    float* Wp2 = Wp1 + 1200;                         // 8960
    float* Wp3 = Wp2 + 8960;                         // 11200
    double* dmeta = (double*)(Wp3 + 11200);          // 42 doubles (8B aligned)
    int* imeta = (int*)(dmeta + 42);                 // 56 ints
    int* qh2 = imeta + 56;                           // B ints
    int* qh3 = qh2 + B;

    setup_kernel<<<1, 256, 0, stream>>>(W1, a1, c1, W2, a2, c2, W3, a3, c3, dmeta, imeta);
    pack_kernel<<<84, 256, 0, stream>>>(W1, W2, W3, Wp1, Wp2, Wp3);
    conv1_kernel<<<B, 256, 0, stream>>>(x, Wp1, b1, imeta, dmeta, h1, qh2);
    conv2_kernel<<<B / 2, 256, 0, stream>>>(h1, Wp2, b2, imeta + 16, qh2, dmeta, h2, qh3);
    conv3_kernel<<<(B + 3) / 4, 256, 0, stream>>>(h2, Wp3, b3, imeta + 36, qh3, Wo, bo, out, B);
}

// Round 7
// 570.165 us; speedup vs baseline: 1.0045x; 1.0045x over previous
//
#include <hip/hip_runtime.h>
#include <hip/hip_bf16.h>

#define EPSV 1e-12
#define RHASH 0.2

__device__ __forceinline__ int fmod2(double t) {
    // floor then mod 2 with numpy semantics (non-negative result)
    return (int)(((long long)floor(t)) & 1LL);
}

__device__ __forceinline__ void load_row6(const float* base, float* r) {
    float2 a0 = *(const float2*)(base);
    float2 a1 = *(const float2*)(base + 2);
    float2 a2 = *(const float2*)(base + 4);
    r[0] = a0.x; r[1] = a0.y; r[2] = a1.x; r[3] = a1.y; r[4] = a2.x; r[5] = a2.y;
}

// 8 FMAs into acc[c][0..7] from rows ca/na (window A) and cb/nb (window B)
#define FMA8(c,kx,w) { float wg=(w); \
  acc[c][0]=fmaf(wg,ca[kx],acc[c][0]); acc[c][1]=fmaf(wg,ca[(kx)+1],acc[c][1]); \
  acc[c][2]=fmaf(wg,na[kx],acc[c][2]); acc[c][3]=fmaf(wg,na[(kx)+1],acc[c][3]); \
  acc[c][4]=fmaf(wg,cb[kx],acc[c][4]); acc[c][5]=fmaf(wg,cb[(kx)+1],acc[c][5]); \
  acc[c][6]=fmaf(wg,nb[kx],acc[c][6]); acc[c][7]=fmaf(wg,nb[(kx)+1],acc[c][7]); }

// 4 FMAs into acc[c][0..3] from rows cur/nxt
#define FMA4(c,kx,w) { float wg=(w); \
  acc[c][0]=fmaf(wg,cur[kx],acc[c][0]); acc[c][1]=fmaf(wg,cur[(kx)+1],acc[c][1]); \
  acc[c][2]=fmaf(wg,nxt[kx],acc[c][2]); acc[c][3]=fmaf(wg,nxt[(kx)+1],acc[c][3]); }

// ---------------------------------------------------------------------------
// setup: per-layer kernel hashes kh[], per-cin a-sums, query constants (double)
// dmeta layout: [0..2]=asum1, [3..18]=asum2, [19..38]=asum3, [39]=qc1,[40]=qc2,[41]=qc3
// imeta layout: [0..15]=kh1, [16..35]=kh2, [36..55]=kh3
// ---------------------------------------------------------------------------
__device__ void layer_setup(const float* W, const float* a, double cval,
                            int Co, int Ci, int* kh, double* asum, double* qc,
                            double* s_norm, float* Wbuf, float* abuf)
{
    const int t = threadIdx.x;
    const int D = Ci * 25;
    for (int i = t; i < Co * D; i += 256) Wbuf[i] = W[i];
    for (int i = t; i < D + 5; i += 256) abuf[i] = a[i];
    __syncthreads();
    if (t < Co) {
        double s = 0;
        for (int j = 0; j < D; ++j) { double w = (double)Wbuf[t * D + j]; s += w * w; }
        s_norm[t] = sqrt(s);
    }
    __syncthreads();
    if (t == 0) {
        double mx = 0;
        for (int i = 0; i < Co; ++i) mx = fmax(mx, s_norm[i]);
        s_norm[23] = 1.0 / (mx + EPSV);
    }
    __syncthreads();
    double scale = s_norm[23];
    if (t < Co) {
        double dp = 0;
        for (int j = 0; j < D; ++j) dp += (double)Wbuf[t * D + j] * (double)abuf[j];
        dp *= scale;
        double n = s_norm[t] * scale;
        double p = n * n;                       // n^2, n^4, n^8, n^16, n^32
        for (int m = 0; m < 5; ++m) { dp += p * (double)abuf[D + m]; p *= p; }
        kh[t] = fmod2((dp + cval) / RHASH);
    }
    if (t >= 64 && t < 64 + Ci) {
        int c = t - 64;
        double s = 0;
        for (int j = 0; j < 25; ++j) s += (double)abuf[c * 25 + j];
        asum[c] = s;
    }
    if (t == 128) {
        double s = 0;
        for (int m = 0; m < 5; ++m) s += (double)abuf[D + m];
        *qc = 0.5 * s + cval;
    }
    __syncthreads();
}

__global__ __launch_bounds__(256) void setup_kernel(
    const float* W1, const float* a1, const float* c1,
    const float* W2, const float* a2, const float* c2,
    const float* W3, const float* a3, const float* c3,
    double* dmeta, int* imeta)
{
    __shared__ float Wbuf[10000];
    __shared__ float abuf[512];
    __shared__ double s_norm[24];
    layer_setup(W1, a1, (double)c1[0], 16, 3,  imeta + 0,  dmeta + 0,  dmeta + 39, s_norm, Wbuf, abuf);
    layer_setup(W2, a2, (double)c2[0], 20, 16, imeta + 16, dmeta + 3,  dmeta + 40, s_norm, Wbuf, abuf);
    layer_setup(W3, a3, (double)c3[0], 20, 20, imeta + 36, dmeta + 19, dmeta + 41, s_norm, Wbuf, abuf);
}

// ---------------------------------------------------------------------------
// weight repack:
// Wp1: [ci3][ky5][kx5][co16]                  = 1200 floats
// Wp2: [ci16][ky5][cog4][28] (j=clocal*5+kx)  = 8960 floats
// Wp3: [ci20][ky5][cog4][28]                  = 11200 floats
// ---------------------------------------------------------------------------
__global__ __launch_bounds__(256) void pack_kernel(const float* W1, const float* W2, const float* W3,
                                                   float* Wp1, float* Wp2, float* Wp3)
{
    int i = blockIdx.x * 256 + threadIdx.x;
    if (i < 1200) {
        int co = i & 15, r = i >> 4;           // r = (ci*5+ky)*5+kx
        int kx = r % 5, r2 = r / 5, ky = r2 % 5, ci = r2 / 5;
        Wp1[i] = W1[co * 75 + ci * 25 + ky * 5 + kx];
    } else if (i < 1200 + 8960) {
        int k = i - 1200;
        int j = k % 28, r = k / 28;            // r = (ci*5+ky)*4+cog
        int cog = r % 4, r2 = r / 4, ky = r2 % 5, ci = r2 / 5;
        Wp2[k] = (j < 25) ? W2[(cog * 5 + j / 5) * 400 + ci * 25 + ky * 5 + (j % 5)] : 0.f;
    } else if (i < 1200 + 8960 + 11200) {
        int k = i - 10160;
        int j = k % 28, r = k / 28;
        int cog = r % 4, r2 = r / 4, ky = r2 % 5, ci = r2 / 5;
        Wp3[k] = (j < 25) ? W3[(cog * 5 + j / 5) * 500 + ci * 25 + ky * 5 + (j % 5)] : 0.f;
    }
}

// ---------------------------------------------------------------------------
// conv1: x[B,3,32,32] -> h1[B,16,16,16]; block=sample;
// thread = (cog2 x py16 x pxp8): 8 co x 8 outputs (2 horizontal quads,
// pooled cols pxp and pxp+8) -> weight b128 amortized over 32 FMAs.
// Fresh row loads per ky (keeps regs ~100 < 128 cap). Fused qh1/qh2.
// ---------------------------------------------------------------------------
__global__ __launch_bounds__(256, 4) void conv1_kernel(
    const float* __restrict__ x, const float* __restrict__ Wp1,
    const float* __restrict__ b1, const int* __restrict__ kh1,
    const double* __restrict__ dmeta, float* __restrict__ h1,
    int* __restrict__ qh2)
{
    __shared__ float xs[3][36][36];
    __shared__ float Ws[1200];
    __shared__ double s_red[3];
    __shared__ double s_ch[16][2];

    const int b = blockIdx.x, t = threadIdx.x;
    const int w = t >> 6, ln = t & 63;

    for (int i = t; i < 3 * 36 * 36; i += 256) (&xs[0][0][0])[i] = 0.f;
    for (int i = t; i < 600; i += 256) ((float2*)Ws)[i] = ((const float2*)Wp1)[i];
    __syncthreads();
    const float2* xb2 = (const float2*)(x + (size_t)b * 3072);
    for (int i = t; i < 1536; i += 256) {
        int idx = i * 2, c = idx >> 10, rem = idx & 1023;
        *(float2*)&xs[c][(rem >> 5) + 2][(rem & 31) + 2] = xb2[i];
    }
    __syncthreads();

    // qh1 from x-tile: wave w (w<3) reduces channel w
    if (w < 3) {
        double s = 0;
        for (int j = 0; j < 16; ++j) {
            int i = ln + 64 * j;
            s += (double)xs[w][(i >> 5) + 2][(i & 31) + 2];
        }
        #pragma unroll
        for (int off = 32; off; off >>= 1) s += __shfl_xor(s, off);
        if (ln == 0) s_red[w] = s;
    }
    __syncthreads();
    double dp = 0, nn = 0;
    #pragma unroll
    for (int c = 0; c < 3; ++c) {
        double cm = s_red[c] * (1.0 / 1024.0);
        dp += cm * dmeta[c]; nn += cm * cm;
    }
    const int qh = fmod2((dp / (5.0 * sqrt(nn) + EPSV) + dmeta[39]) / RHASH);

    const int cog = t >> 7, r7 = t & 127;
    const int py = r7 >> 3, pxp = r7 & 7;
    const int y0 = 2 * py, x0a = 2 * pxp, x0b = 2 * pxp + 16;

    float acc[8][8];
    #pragma unroll
    for (int c = 0; c < 8; ++c) {
        float bb = b1[cog * 8 + c];
        #pragma unroll
        for (int j = 0; j < 8; ++j) acc[c][j] = bb;
    }

    #pragma unroll
    for (int ci = 0; ci < 3; ++ci) {
        #pragma unroll
        for (int ky = 0; ky < 5; ++ky) {
            float ca[6], na[6], cb[6], nb[6];
            load_row6(&xs[ci][y0 + ky][x0a],     ca);
            load_row6(&xs[ci][y0 + ky + 1][x0a], na);
            load_row6(&xs[ci][y0 + ky][x0b],     cb);
            load_row6(&xs[ci][y0 + ky + 1][x0b], nb);
            const float4* wq = (const float4*)&Ws[((ci * 5 + ky) * 5) * 16 + cog * 8];
            #pragma unroll
            for (int kx = 0; kx < 5; ++kx) {
                float4 w0 = wq[kx * 4];          // co 0..3 of this half
                float4 w1 = wq[kx * 4 + 1];      // co 4..7
                FMA8(0, kx, w0.x) FMA8(1, kx, w0.y) FMA8(2, kx, w0.z) FMA8(3, kx, w0.w)
                FMA8(4, kx, w1.x) FMA8(5, kx, w1.y) FMA8(6, kx, w1.z) FMA8(7, kx, w1.w)
            }
        }
    }

    // store masked pooled outputs + per-channel sums for qh2
    float* hb = h1 + (size_t)b * 4096 + py * 16 + pxp;
    double csum[8];
    #pragma unroll
    for (int c = 0; c < 8; ++c) {
        int co = cog * 8 + c;
        float mask = (kh1[co] == qh) ? 1.f : 0.f;
        float mA = fmaxf(fmaxf(acc[c][0], acc[c][1]), fmaxf(acc[c][2], acc[c][3]));
        float mB = fmaxf(fmaxf(acc[c][4], acc[c][5]), fmaxf(acc[c][6], acc[c][7]));
        float vA = fmaxf(mA, 0.f) * mask;
        float vB = fmaxf(mB, 0.f) * mask;
        hb[co * 256]     = vA;
        hb[co * 256 + 8] = vB;
        csum[c] = (double)vA + (double)vB;
    }
    #pragma unroll
    for (int c = 0; c < 8; ++c) {
        double s = csum[c];
        #pragma unroll
        for (int off = 32; off; off >>= 1) s += __shfl_xor(s, off);
        if (ln == 0) s_ch[cog * 8 + c][w & 1] = s;
    }
    __syncthreads();
    if (t == 0) {
        double dp2 = 0, nn2 = 0;
        #pragma unroll
        for (int c = 0; c < 16; ++c) {
            double cm = (s_ch[c][0] + s_ch[c][1]) * (1.0 / 256.0);
            dp2 += cm * dmeta[3 + c]; nn2 += cm * cm;
        }
        qh2[b] = fmod2((dp2 / (5.0 * sqrt(nn2) + EPSV) + dmeta[40]) / RHASH);
    }
}

// ---------------------------------------------------------------------------
// conv2: h1[B,16,16,16] -> h2[B,20,8,8]; block = 2 samples;
// thread = (cog4 x [s2 x py8 x pxp4]): 5 co x 8 outputs.
// Weights consumed one float4 at a time (no 28-reg cache -> no spills).
// K chunked 4 ci (LDS 21.8KB); rolling rows; fused qh3.
// ---------------------------------------------------------------------------
__global__ __launch_bounds__(256, 4) void conv2_kernel(
    const float* __restrict__ h1, const float* __restrict__ Wp2,
    const float* __restrict__ b2, const int* __restrict__ kh2,
    const int* __restrict__ qh2, const double* __restrict__ dmeta,
    float* __restrict__ h2, int* __restrict__ qh3)
{
    __shared__ float xs[2][4][20][20];
    __shared__ float Ws[2240];           // [ci4][ky5][cog4][28]
    __shared__ double s_ch[2][20];

    const int b0 = blockIdx.x * 2, t = threadIdx.x;
    const int cog = t >> 6, slot = t & 63;
    const int s = slot >> 5, py = (slot >> 2) & 7, pxp = slot & 3;
    const int y0 = 2 * py, x0a = 2 * pxp, x0b = 2 * pxp + 8;

    for (int i = t; i < 3200; i += 256) (&xs[0][0][0][0])[i] = 0.f;

    const int qh = qh2[b0 + s];
    float acc[5][8];
    #pragma unroll
    for (int c = 0; c < 5; ++c) {
        float bb = b2[cog * 5 + c];
        #pragma unroll
        for (int j = 0; j < 8; ++j) acc[c][j] = bb;
    }
    __syncthreads();

    for (int ch = 0; ch < 4; ++ch) {
        for (int i = t; i < 1120; i += 256)
            ((float2*)Ws)[i] = ((const float2*)(Wp2 + ch * 2240))[i];
        for (int i = t; i < 1024; i += 256) {
            int ss = i >> 9, r = i & 511, ci = r >> 7, rr = r & 127, p2 = rr * 2;
            *(float2*)&xs[ss][ci][(p2 >> 4) + 2][(p2 & 15) + 2] =
                ((const float2*)(h1 + (size_t)(b0 + ss) * 4096 + (ch * 4 + ci) * 256))[rr];
        }
        __syncthreads();

        #pragma unroll
        for (int ci = 0; ci < 4; ++ci) {
            float ca[6], na[6], cb[6], nb[6];
            load_row6(&xs[s][ci][y0][x0a], ca);
            load_row6(&xs[s][ci][y0 + 1][x0a], na);
            load_row6(&xs[s][ci][y0][x0b], cb);
            load_row6(&xs[s][ci][y0 + 1][x0b], nb);
            #pragma unroll
            for (int ky = 0; ky < 5; ++ky) {
                const float* wrow = &Ws[((ci * 5 + ky) * 4 + cog) * 28];
                const float4* wq = (const float4*)wrow;
                float4 q;
                q = wq[0]; FMA8(0, 0, q.x) FMA8(0, 1, q.y) FMA8(0, 2, q.z) FMA8(0, 3, q.w)
                q = wq[1]; FMA8(0, 4, q.x) FMA8(1, 0, q.y) FMA8(1, 1, q.z) FMA8(1, 2, q.w)
                q = wq[2]; FMA8(1, 3, q.x) FMA8(1, 4, q.y) FMA8(2, 0, q.z) FMA8(2, 1, q.w)
                q = wq[3]; FMA8(2, 2, q.x) FMA8(2, 3, q.y) FMA8(2, 4, q.z) FMA8(3, 0, q.w)
                q = wq[4]; FMA8(3, 1, q.x) FMA8(3, 2, q.y) FMA8(3, 3, q.z) FMA8(3, 4, q.w)
                q = wq[5]; FMA8(4, 0, q.x) FMA8(4, 1, q.y) FMA8(4, 2, q.z) FMA8(4, 3, q.w)
                FMA8(4, 4, wrow[24])
                if (ky < 4) {
                    #pragma unroll
                    for (int j = 0; j < 6; ++j) { ca[j] = na[j]; cb[j] = nb[j]; }
                    load_row6(&xs[s][ci][y0 + ky + 2][x0a], na);
                    load_row6(&xs[s][ci][y0 + ky + 2][x0b], nb);
                }
            }
        }
        __syncthreads();
    }

    // store 2 pooled outputs per co + fused qh3 (per-sample half-wave reduce)
    float* ob = h2 + (size_t)(b0 + s) * 1280 + py * 8 + pxp;
    double csum[5];
    #pragma unroll
    for (int c = 0; c < 5; ++c) {
        int co = cog * 5 + c;
        float mask = (kh2[co] == qh) ? 1.f : 0.f;
        float mA = fmaxf(fmaxf(acc[c][0], acc[c][1]), fmaxf(acc[c][2], acc[c][3]));
        float mB = fmaxf(fmaxf(acc[c][4], acc[c][5]), fmaxf(acc[c][6], acc[c][7]));
        float vA = fmaxf(mA, 0.f) * mask;
        float vB = fmaxf(mB, 0.f) * mask;
        ob[co * 64]     = vA;
        ob[co * 64 + 4] = vB;
        csum[c] = (double)vA + (double)vB;
    }
    #pragma unroll
    for (int c = 0; c < 5; ++c) {
        double sv = csum[c];
        #pragma unroll
        for (int off = 16; off; off >>= 1) sv += __shfl_xor(sv, off);  // within 32-lane half
        if ((slot & 31) == 0) s_ch[s][cog * 5 + c] = sv;
    }
    __syncthreads();
    if (t < 2) {
        double dp2 = 0, nn2 = 0;
        #pragma unroll
        for (int c = 0; c < 20; ++c) {
            double cm = s_ch[t][c] * (1.0 / 64.0);
            dp2 += cm * dmeta[19 + c]; nn2 += cm * cm;
        }
        qh3[b0 + t] = fmod2((dp2 / (5.0 * sqrt(nn2) + EPSV) + dmeta[41]) / RHASH);
    }
}

// ---------------------------------------------------------------------------
// conv3 + linear: h2[B,20,8,8] -> out[B,10]; block = 4 samples;
// thread = (s4 x cog4 x pos16), 5 co x 2x2 quad; K chunked in 4x5 ci;
// rolling rows; chunk-consumed weights; stride 12 (conflict-free broadcast).
// ---------------------------------------------------------------------------
__global__ __launch_bounds__(256, 4) void conv3_kernel(
    const float* __restrict__ h2, const float* __restrict__ Wp3,
    const float* __restrict__ b3, const int* __restrict__ kh3,
    const int* __restrict__ qh3,
    const float* __restrict__ Wo, const float* __restrict__ bo,
    float* __restrict__ out, int B)
{
    __shared__ float xs[4][5][12][12];
    __shared__ float Ws[2800];           // [ci5][ky5][cog4][28]
    __shared__ float flat[4][320];

    const int b0 = blockIdx.x * 4, t = threadIdx.x;
    const int s = t >> 6, q0 = t & 63, cog = q0 >> 4, pos = q0 & 15;
    const int py = pos >> 2, px = pos & 3;
    const int y0 = 2 * py, x0 = 2 * px;
    const int b = b0 + s;

    for (int i = t; i < 4 * 5 * 144; i += 256) (&xs[0][0][0][0])[i] = 0.f;

    const int qh = (b < B) ? qh3[b] : 0;
    float acc[5][4];
    #pragma unroll
    for (int c = 0; c < 5; ++c) {
        float bb = b3[cog * 5 + c];
        acc[c][0] = bb; acc[c][1] = bb; acc[c][2] = bb; acc[c][3] = bb;
    }
    __syncthreads();

    for (int ch = 0; ch < 4; ++ch) {
        for (int i = t; i < 1400; i += 256)
            ((float2*)Ws)[i] = ((const float2*)(Wp3 + ch * 2800))[i];
        for (int i = t; i < 640; i += 256) {
            int ss = i / 160, r = i - ss * 160, ci = r >> 5, rr = r & 31, p2 = rr * 2;
            if (b0 + ss < B)
                *(float2*)&xs[ss][ci][(p2 >> 3) + 2][(p2 & 7) + 2] =
                    ((const float2*)(h2 + (size_t)(b0 + ss) * 1280 + (ch * 5 + ci) * 64))[rr];
        }
        __syncthreads();

        #pragma unroll
        for (int ci = 0; ci < 5; ++ci) {
            float cur[6], nxt[6];
            load_row6(&xs[s][ci][y0][x0], cur);
            load_row6(&xs[s][ci][y0 + 1][x0], nxt);
            #pragma unroll
            for (int ky = 0; ky < 5; ++ky) {
                const float* wrow = &Ws[((ci * 5 + ky) * 4 + cog) * 28];
                const float4* wq = (const float4*)wrow;
                float4 q;
                q = wq[0]; FMA4(0, 0, q.x) FMA4(0, 1, q.y) FMA4(0, 2, q.z) FMA4(0, 3, q.w)
                q = wq[1]; FMA4(0, 4, q.x) FMA4(1, 0, q.y) FMA4(1, 1, q.z) FMA4(1, 2, q.w)
                q = wq[2]; FMA4(1, 3, q.x) FMA4(1, 4, q.y) FMA4(2, 0, q.z) FMA4(2, 1, q.w)
                q = wq[3]; FMA4(2, 2, q.x) FMA4(2, 3, q.y) FMA4(2, 4, q.z) FMA4(3, 0, q.w)
                q = wq[4]; FMA4(3, 1, q.x) FMA4(3, 2, q.y) FMA4(3, 3, q.z) FMA4(3, 4, q.w)
                q = wq[5]; FMA4(4, 0, q.x) FMA4(4, 1, q.y) FMA4(4, 2, q.z) FMA4(4, 3, q.w)
                FMA4(4, 4, wrow[24])
                if (ky < 4) {
                    #pragma unroll
                    for (int j = 0; j < 6; ++j) cur[j] = nxt[j];
                    load_row6(&xs[s][ci][y0 + ky + 2][x0], nxt);
                }
            }
        }
        __syncthreads();
    }

    #pragma unroll
    for (int c = 0; c < 5; ++c) {
        int co = cog * 5 + c;
        float m = fmaxf(fmaxf(acc[c][0], acc[c][1]), fmaxf(acc[c][2], acc[c][3]));
        flat[s][co * 16 + pos] = fmaxf(m, 0.f) * ((kh3[co] == qh) ? 1.f : 0.f);
    }
    __syncthreads();

    // linear 320->10 for 4 samples: 40 (s,o) pairs x 4 lanes each
    if (t < 160) {
        const int g = t >> 2, qq = t & 3;
        const int ss = g / 10, o = g - ss * 10;
        float a = 0.f;
        const float* wr = Wo + o * 320;
        for (int k = qq; k < 320; k += 4) a = fmaf(flat[ss][k], wr[k], a);
        a += __shfl_xor(a, 1);
        a += __shfl_xor(a, 2);
        if (qq == 0 && b0 + ss < B) out[(size_t)(b0 + ss) * 10 + o] = a + bo[o];
    }
}

// ---------------------------------------------------------------------------
extern "C" void kernel_launch(void* const* d_in, const int* in_sizes, int n_in,
                              void* d_out, int out_size, void* d_ws, size_t ws_size,
                              hipStream_t stream)
{
    const float* x  = (const float*)d_in[0];
    const float* W1 = (const float*)d_in[1];
    const float* b1 = (const float*)d_in[2];
    const float* a1 = (const float*)d_in[3];
    const float* c1 = (const float*)d_in[4];
    const float* W2 = (const float*)d_in[5];
    const float* b2 = (const float*)d_in[6];
    const float* a2 = (const float*)d_in[7];
    const float* c2 = (const float*)d_in[8];
    const float* W3 = (const float*)d_in[9];
    const float* b3 = (const float*)d_in[10];
    const float* a3 = (const float*)d_in[11];
    const float* c3 = (const float*)d_in[12];
    const float* Wo = (const float*)d_in[13];
    const float* bo = (const float*)d_in[14];
    float* out = (float*)d_out;

    const int B = in_sizes[0] / 3072;   // 4096 (even)

    float* h1  = (float*)d_ws;                       // B*4096 f32
    float* h2  = h1 + (size_t)B * 4096;              // B*1280 f32
    float* Wp1 = h2 + (size_t)B * 1280;              // 1200
    float* Wp2 = Wp1 + 1200;                         // 8960
    float* Wp3 = Wp2 + 8960;                         // 11200
    double* dmeta = (double*)(Wp3 + 11200);          // 42 doubles (8B aligned)
    int* imeta = (int*)(dmeta + 42);                 // 56 ints
    int* qh2 = imeta + 56;                           // B ints
    int* qh3 = qh2 + B;

    setup_kernel<<<1, 256, 0, stream>>>(W1, a1, c1, W2, a2, c2, W3, a3, c3, dmeta, imeta);
    pack_kernel<<<84, 256, 0, stream>>>(W1, W2, W3, Wp1, Wp2, Wp3);
    conv1_kernel<<<B, 256, 0, stream>>>(x, Wp1, b1, imeta, dmeta, h1, qh2);
    conv2_kernel<<<B / 2, 256, 0, stream>>>(h1, Wp2, b2, imeta + 16, qh2, dmeta, h2, qh3);
    conv3_kernel<<<(B + 3) / 4, 256, 0, stream>>>(h2, Wp3, b3, imeta + 36, qh3, Wo, bo, out, B);
}

// Round 8
// 522.685 us; speedup vs baseline: 1.0958x; 1.0908x over previous
//
#include <hip/hip_runtime.h>
#include <hip/hip_bf16.h>

#define EPSV 1e-12
#define RHASH 0.2

__device__ __forceinline__ int fmod2(double t) {
    // floor then mod 2 with numpy semantics (non-negative result)
    return (int)(((long long)floor(t)) & 1LL);
}

__device__ __forceinline__ void load_row6(const float* base, float* r) {
    float2 a0 = *(const float2*)(base);
    float2 a1 = *(const float2*)(base + 2);
    float2 a2 = *(const float2*)(base + 4);
    r[0] = a0.x; r[1] = a0.y; r[2] = a1.x; r[3] = a1.y; r[4] = a2.x; r[5] = a2.y;
}

// 8 FMAs into acc[c][0..7] from rows ca/na (window A) and cb/nb (window B)
#define FMA8(c,kx,w) { float wg=(w); \
  acc[c][0]=fmaf(wg,ca[kx],acc[c][0]); acc[c][1]=fmaf(wg,ca[(kx)+1],acc[c][1]); \
  acc[c][2]=fmaf(wg,na[kx],acc[c][2]); acc[c][3]=fmaf(wg,na[(kx)+1],acc[c][3]); \
  acc[c][4]=fmaf(wg,cb[kx],acc[c][4]); acc[c][5]=fmaf(wg,cb[(kx)+1],acc[c][5]); \
  acc[c][6]=fmaf(wg,nb[kx],acc[c][6]); acc[c][7]=fmaf(wg,nb[(kx)+1],acc[c][7]); }

// 4 FMAs into acc[c][0..3] from rows cur/nxt
#define FMA4(c,kx,w) { float wg=(w); \
  acc[c][0]=fmaf(wg,cur[kx],acc[c][0]); acc[c][1]=fmaf(wg,cur[(kx)+1],acc[c][1]); \
  acc[c][2]=fmaf(wg,nxt[kx],acc[c][2]); acc[c][3]=fmaf(wg,nxt[(kx)+1],acc[c][3]); }

// ---------------------------------------------------------------------------
// setup: per-layer kernel hashes kh[], per-cin a-sums, query constants (double)
// dmeta layout: [0..2]=asum1, [3..18]=asum2, [19..38]=asum3, [39]=qc1,[40]=qc2,[41]=qc3
// imeta layout: [0..15]=kh1, [16..35]=kh2, [36..55]=kh3
// ---------------------------------------------------------------------------
__device__ void layer_setup(const float* W, const float* a, double cval,
                            int Co, int Ci, int* kh, double* asum, double* qc,
                            double* s_norm, float* Wbuf, float* abuf)
{
    const int t = threadIdx.x;
    const int D = Ci * 25;
    for (int i = t; i < Co * D; i += 256) Wbuf[i] = W[i];
    for (int i = t; i < D + 5; i += 256) abuf[i] = a[i];
    __syncthreads();
    if (t < Co) {
        double s = 0;
        for (int j = 0; j < D; ++j) { double w = (double)Wbuf[t * D + j]; s += w * w; }
        s_norm[t] = sqrt(s);
    }
    __syncthreads();
    if (t == 0) {
        double mx = 0;
        for (int i = 0; i < Co; ++i) mx = fmax(mx, s_norm[i]);
        s_norm[23] = 1.0 / (mx + EPSV);
    }
    __syncthreads();
    double scale = s_norm[23];
    if (t < Co) {
        double dp = 0;
        for (int j = 0; j < D; ++j) dp += (double)Wbuf[t * D + j] * (double)abuf[j];
        dp *= scale;
        double n = s_norm[t] * scale;
        double p = n * n;                       // n^2, n^4, n^8, n^16, n^32
        for (int m = 0; m < 5; ++m) { dp += p * (double)abuf[D + m]; p *= p; }
        kh[t] = fmod2((dp + cval) / RHASH);
    }
    if (t >= 64 && t < 64 + Ci) {
        int c = t - 64;
        double s = 0;
        for (int j = 0; j < 25; ++j) s += (double)abuf[c * 25 + j];
        asum[c] = s;
    }
    if (t == 128) {
        double s = 0;
        for (int m = 0; m < 5; ++m) s += (double)abuf[D + m];
        *qc = 0.5 * s + cval;
    }
    __syncthreads();
}

__global__ __launch_bounds__(256) void setup_kernel(
    const float* W1, const float* a1, const float* c1,
    const float* W2, const float* a2, const float* c2,
    const float* W3, const float* a3, const float* c3,
    double* dmeta, int* imeta)
{
    __shared__ float Wbuf[10000];
    __shared__ float abuf[512];
    __shared__ double s_norm[24];
    layer_setup(W1, a1, (double)c1[0], 16, 3,  imeta + 0,  dmeta + 0,  dmeta + 39, s_norm, Wbuf, abuf);
    layer_setup(W2, a2, (double)c2[0], 20, 16, imeta + 16, dmeta + 3,  dmeta + 40, s_norm, Wbuf, abuf);
    layer_setup(W3, a3, (double)c3[0], 20, 20, imeta + 36, dmeta + 19, dmeta + 41, s_norm, Wbuf, abuf);
}

// ---------------------------------------------------------------------------
// weight repack:
// Wp1: [ci3][ky5][kx5][co16]                  = 1200 floats
// Wp2: [ci16][ky5][cog4][28] (j=clocal*5+kx)  = 8960 floats
// Wp3: [ci20][ky5][cog4][28]                  = 11200 floats
// ---------------------------------------------------------------------------
__global__ __launch_bounds__(256) void pack_kernel(const float* W1, const float* W2, const float* W3,
                                                   float* Wp1, float* Wp2, float* Wp3)
{
    int i = blockIdx.x * 256 + threadIdx.x;
    if (i < 1200) {
        int co = i & 15, r = i >> 4;           // r = (ci*5+ky)*5+kx
        int kx = r % 5, r2 = r / 5, ky = r2 % 5, ci = r2 / 5;
        Wp1[i] = W1[co * 75 + ci * 25 + ky * 5 + kx];
    } else if (i < 1200 + 8960) {
        int k = i - 1200;
        int j = k % 28, r = k / 28;            // r = (ci*5+ky)*4+cog
        int cog = r % 4, r2 = r / 4, ky = r2 % 5, ci = r2 / 5;
        Wp2[k] = (j < 25) ? W2[(cog * 5 + j / 5) * 400 + ci * 25 + ky * 5 + (j % 5)] : 0.f;
    } else if (i < 1200 + 8960 + 11200) {
        int k = i - 10160;
        int j = k % 28, r = k / 28;
        int cog = r % 4, r2 = r / 4, ky = r2 % 5, ci = r2 / 5;
        Wp3[k] = (j < 25) ? W3[(cog * 5 + j / 5) * 500 + ci * 25 + ky * 5 + (j % 5)] : 0.f;
    }
}

// ---------------------------------------------------------------------------
// conv1: x[B,3,32,32] -> h1[B,16,16,16]; block=sample;
// thread = (cog2 x py16 x pxp8): 8 co x 8 outputs (2 horizontal quads,
// pooled cols pxp and pxp+8) -> weight b128 amortized over 32 FMAs.
// NO register-capping launch bound (r7's (256,4) caused VGPR=64 + spills).
// Fused qh1/qh2.
// ---------------------------------------------------------------------------
__global__ __launch_bounds__(256) void conv1_kernel(
    const float* __restrict__ x, const float* __restrict__ Wp1,
    const float* __restrict__ b1, const int* __restrict__ kh1,
    const double* __restrict__ dmeta, float* __restrict__ h1,
    int* __restrict__ qh2)
{
    __shared__ float xs[3][36][36];
    __shared__ float Ws[1200];
    __shared__ double s_red[3];
    __shared__ double s_ch[16][2];

    const int b = blockIdx.x, t = threadIdx.x;
    const int w = t >> 6, ln = t & 63;

    for (int i = t; i < 3 * 36 * 36; i += 256) (&xs[0][0][0])[i] = 0.f;
    for (int i = t; i < 600; i += 256) ((float2*)Ws)[i] = ((const float2*)Wp1)[i];
    __syncthreads();
    const float2* xb2 = (const float2*)(x + (size_t)b * 3072);
    for (int i = t; i < 1536; i += 256) {
        int idx = i * 2, c = idx >> 10, rem = idx & 1023;
        *(float2*)&xs[c][(rem >> 5) + 2][(rem & 31) + 2] = xb2[i];
    }
    __syncthreads();

    // qh1 from x-tile: wave w (w<3) reduces channel w
    if (w < 3) {
        double s = 0;
        for (int j = 0; j < 16; ++j) {
            int i = ln + 64 * j;
            s += (double)xs[w][(i >> 5) + 2][(i & 31) + 2];
        }
        #pragma unroll
        for (int off = 32; off; off >>= 1) s += __shfl_xor(s, off);
        if (ln == 0) s_red[w] = s;
    }
    __syncthreads();
    double dp = 0, nn = 0;
    #pragma unroll
    for (int c = 0; c < 3; ++c) {
        double cm = s_red[c] * (1.0 / 1024.0);
        dp += cm * dmeta[c]; nn += cm * cm;
    }
    const int qh = fmod2((dp / (5.0 * sqrt(nn) + EPSV) + dmeta[39]) / RHASH);

    const int cog = t >> 7, r7 = t & 127;
    const int py = r7 >> 3, pxp = r7 & 7;
    const int y0 = 2 * py, x0a = 2 * pxp, x0b = 2 * pxp + 16;

    float acc[8][8];
    #pragma unroll
    for (int c = 0; c < 8; ++c) {
        float bb = b1[cog * 8 + c];
        #pragma unroll
        for (int j = 0; j < 8; ++j) acc[c][j] = bb;
    }

    #pragma unroll
    for (int ci = 0; ci < 3; ++ci) {
        #pragma unroll
        for (int ky = 0; ky < 5; ++ky) {
            float ca[6], na[6], cb[6], nb[6];
            load_row6(&xs[ci][y0 + ky][x0a],     ca);
            load_row6(&xs[ci][y0 + ky + 1][x0a], na);
            load_row6(&xs[ci][y0 + ky][x0b],     cb);
            load_row6(&xs[ci][y0 + ky + 1][x0b], nb);
            const float4* wq = (const float4*)&Ws[((ci * 5 + ky) * 5) * 16 + cog * 8];
            #pragma unroll
            for (int kx = 0; kx < 5; ++kx) {
                float4 w0 = wq[kx * 4];          // co 0..3 of this half
                float4 w1 = wq[kx * 4 + 1];      // co 4..7
                FMA8(0, kx, w0.x) FMA8(1, kx, w0.y) FMA8(2, kx, w0.z) FMA8(3, kx, w0.w)
                FMA8(4, kx, w1.x) FMA8(5, kx, w1.y) FMA8(6, kx, w1.z) FMA8(7, kx, w1.w)
            }
        }
    }

    // store masked pooled outputs + per-channel sums for qh2
    float* hb = h1 + (size_t)b * 4096 + py * 16 + pxp;
    double csum[8];
    #pragma unroll
    for (int c = 0; c < 8; ++c) {
        int co = cog * 8 + c;
        float mask = (kh1[co] == qh) ? 1.f : 0.f;
        float mA = fmaxf(fmaxf(acc[c][0], acc[c][1]), fmaxf(acc[c][2], acc[c][3]));
        float mB = fmaxf(fmaxf(acc[c][4], acc[c][5]), fmaxf(acc[c][6], acc[c][7]));
        float vA = fmaxf(mA, 0.f) * mask;
        float vB = fmaxf(mB, 0.f) * mask;
        hb[co * 256]     = vA;
        hb[co * 256 + 8] = vB;
        csum[c] = (double)vA + (double)vB;
    }
    #pragma unroll
    for (int c = 0; c < 8; ++c) {
        double s = csum[c];
        #pragma unroll
        for (int off = 32; off; off >>= 1) s += __shfl_xor(s, off);
        if (ln == 0) s_ch[cog * 8 + c][w & 1] = s;
    }
    __syncthreads();
    if (t == 0) {
        double dp2 = 0, nn2 = 0;
        #pragma unroll
        for (int c = 0; c < 16; ++c) {
            double cm = (s_ch[c][0] + s_ch[c][1]) * (1.0 / 256.0);
            dp2 += cm * dmeta[3 + c]; nn2 += cm * cm;
        }
        qh2[b] = fmod2((dp2 / (5.0 * sqrt(nn2) + EPSV) + dmeta[40]) / RHASH);
    }
}

// ---------------------------------------------------------------------------
// conv2: h1[B,16,16,16] -> h2[B,20,8,8]; block = 1 sample (r4-measured-best:
// 223us). thread = (cog4 x pos64): 5 co x 2x2 quad. K chunked 2x8 ci;
// wv[28] weight cache; fresh 2-row loads per ky. Fused qh3 epilogue.
// LDS = 12.8 + 17.9 = 30.7KB.
// ---------------------------------------------------------------------------
__global__ __launch_bounds__(256) void conv2_kernel(
    const float* __restrict__ h1, const float* __restrict__ Wp2,
    const float* __restrict__ b2, const int* __restrict__ kh2,
    const int* __restrict__ qh2, const double* __restrict__ dmeta,
    float* __restrict__ h2, int* __restrict__ qh3)
{
    __shared__ float xs[8][20][20];
    __shared__ float Ws[4480];           // [ci8][ky5][cog4][28]
    __shared__ double s_ch[20];

    const int b = blockIdx.x, t = threadIdx.x;
    const int cog = t >> 6, pos = t & 63;
    const int py = pos >> 3, px = pos & 7;
    const int y0 = 2 * py, x0 = 2 * px;

    for (int i = t; i < 3200; i += 256) (&xs[0][0][0])[i] = 0.f;

    const int qh = qh2[b];
    float acc[5][4];
    #pragma unroll
    for (int c = 0; c < 5; ++c) {
        float bb = b2[cog * 5 + c];
        acc[c][0] = bb; acc[c][1] = bb; acc[c][2] = bb; acc[c][3] = bb;
    }
    __syncthreads();

    for (int ch = 0; ch < 2; ++ch) {
        for (int i = t; i < 2240; i += 256)
            ((float2*)Ws)[i] = ((const float2*)(Wp2 + ch * 4480))[i];
        const float2* src = (const float2*)(h1 + (size_t)b * 4096 + ch * 2048);
        for (int i = t; i < 1024; i += 256) {
            int ci = i >> 7, r = i & 127, p2 = r * 2;
            *(float2*)&xs[ci][(p2 >> 4) + 2][(p2 & 15) + 2] = src[i];
        }
        __syncthreads();

        for (int ci = 0; ci < 8; ++ci) {
            #pragma unroll
            for (int ky = 0; ky < 5; ++ky) {
                float xr0[6], xr1[6];
                load_row6(&xs[ci][y0 + ky][x0],     xr0);
                load_row6(&xs[ci][y0 + ky + 1][x0], xr1);
                float wv[28];
                const float4* wp = (const float4*)&Ws[((ci * 5 + ky) * 4 + cog) * 28];
                *(float4*)&wv[0]  = wp[0];
                *(float4*)&wv[4]  = wp[1];
                *(float4*)&wv[8]  = wp[2];
                *(float4*)&wv[12] = wp[3];
                *(float4*)&wv[16] = wp[4];
                *(float4*)&wv[20] = wp[5];
                *(float4*)&wv[24] = wp[6];
                #pragma unroll
                for (int c = 0; c < 5; ++c) {
                    #pragma unroll
                    for (int kx = 0; kx < 5; ++kx) {
                        float wgt = wv[c * 5 + kx];
                        acc[c][0] = fmaf(wgt, xr0[kx],     acc[c][0]);
                        acc[c][1] = fmaf(wgt, xr0[kx + 1], acc[c][1]);
                        acc[c][2] = fmaf(wgt, xr1[kx],     acc[c][2]);
                        acc[c][3] = fmaf(wgt, xr1[kx + 1], acc[c][3]);
                    }
                }
            }
        }
        __syncthreads();
    }

    // store masked pooled outputs + fused qh3 (wave cog owns channels 5cog..)
    float* ob = h2 + (size_t)b * 1280 + pos;
    double csum[5];
    #pragma unroll
    for (int c = 0; c < 5; ++c) {
        int co = cog * 5 + c;
        float mask = (kh2[co] == qh) ? 1.f : 0.f;
        float m = fmaxf(fmaxf(acc[c][0], acc[c][1]), fmaxf(acc[c][2], acc[c][3]));
        float v = fmaxf(m, 0.f) * mask;
        ob[co * 64] = v;
        csum[c] = (double)v;
    }
    #pragma unroll
    for (int c = 0; c < 5; ++c) {
        double sv = csum[c];
        #pragma unroll
        for (int off = 32; off; off >>= 1) sv += __shfl_xor(sv, off);
        if (pos == 0) s_ch[cog * 5 + c] = sv;
    }
    __syncthreads();
    if (t == 0) {
        double dp2 = 0, nn2 = 0;
        #pragma unroll
        for (int c = 0; c < 20; ++c) {
            double cm = s_ch[c] * (1.0 / 64.0);
            dp2 += cm * dmeta[19 + c]; nn2 += cm * cm;
        }
        qh3[b] = fmod2((dp2 / (5.0 * sqrt(nn2) + EPSV) + dmeta[41]) / RHASH);
    }
}

// ---------------------------------------------------------------------------
// conv3 + linear: h2[B,20,8,8] -> out[B,10]; block = 4 samples;
// thread = (s4 x cog4 x pos16), 5 co x 2x2 quad; K chunked in 4x5 ci;
// rolling rows; chunk-consumed weights; stride 12 (conflict-free broadcast).
// ---------------------------------------------------------------------------
__global__ __launch_bounds__(256) void conv3_kernel(
    const float* __restrict__ h2, const float* __restrict__ Wp3,
    const float* __restrict__ b3, const int* __restrict__ kh3,
    const int* __restrict__ qh3,
    const float* __restrict__ Wo, const float* __restrict__ bo,
    float* __restrict__ out, int B)
{
    __shared__ float xs[4][5][12][12];
    __shared__ float Ws[2800];           // [ci5][ky5][cog4][28]
    __shared__ float flat[4][320];

    const int b0 = blockIdx.x * 4, t = threadIdx.x;
    const int s = t >> 6, q0 = t & 63, cog = q0 >> 4, pos = q0 & 15;
    const int py = pos >> 2, px = pos & 3;
    const int y0 = 2 * py, x0 = 2 * px;
    const int b = b0 + s;

    for (int i = t; i < 4 * 5 * 144; i += 256) (&xs[0][0][0][0])[i] = 0.f;

    const int qh = (b < B) ? qh3[b] : 0;
    float acc[5][4];
    #pragma unroll
    for (int c = 0; c < 5; ++c) {
        float bb = b3[cog * 5 + c];
        acc[c][0] = bb; acc[c][1] = bb; acc[c][2] = bb; acc[c][3] = bb;
    }
    __syncthreads();

    for (int ch = 0; ch < 4; ++ch) {
        for (int i = t; i < 1400; i += 256)
            ((float2*)Ws)[i] = ((const float2*)(Wp3 + ch * 2800))[i];
        for (int i = t; i < 640; i += 256) {
            int ss = i / 160, r = i - ss * 160, ci = r >> 5, rr = r & 31, p2 = rr * 2;
            if (b0 + ss < B)
                *(float2*)&xs[ss][ci][(p2 >> 3) + 2][(p2 & 7) + 2] =
                    ((const float2*)(h2 + (size_t)(b0 + ss) * 1280 + (ch * 5 + ci) * 64))[rr];
        }
        __syncthreads();

        #pragma unroll
        for (int ci = 0; ci < 5; ++ci) {
            float cur[6], nxt[6];
            load_row6(&xs[s][ci][y0][x0], cur);
            load_row6(&xs[s][ci][y0 + 1][x0], nxt);
            #pragma unroll
            for (int ky = 0; ky < 5; ++ky) {
                const float* wrow = &Ws[((ci * 5 + ky) * 4 + cog) * 28];
                const float4* wq = (const float4*)wrow;
                float4 q;
                q = wq[0]; FMA4(0, 0, q.x) FMA4(0, 1, q.y) FMA4(0, 2, q.z) FMA4(0, 3, q.w)
                q = wq[1]; FMA4(0, 4, q.x) FMA4(1, 0, q.y) FMA4(1, 1, q.z) FMA4(1, 2, q.w)
                q = wq[2]; FMA4(1, 3, q.x) FMA4(1, 4, q.y) FMA4(2, 0, q.z) FMA4(2, 1, q.w)
                q = wq[3]; FMA4(2, 2, q.x) FMA4(2, 3, q.y) FMA4(2, 4, q.z) FMA4(3, 0, q.w)
                q = wq[4]; FMA4(3, 1, q.x) FMA4(3, 2, q.y) FMA4(3, 3, q.z) FMA4(3, 4, q.w)
                q = wq[5]; FMA4(4, 0, q.x) FMA4(4, 1, q.y) FMA4(4, 2, q.z) FMA4(4, 3, q.w)
                FMA4(4, 4, wrow[24])
                if (ky < 4) {
                    #pragma unroll
                    for (int j = 0; j < 6; ++j) cur[j] = nxt[j];
                    load_row6(&xs[s][ci][y0 + ky + 2][x0], nxt);
                }
            }
        }
        __syncthreads();
    }

    #pragma unroll
    for (int c = 0; c < 5; ++c) {
        int co = cog * 5 + c;
        float m = fmaxf(fmaxf(acc[c][0], acc[c][1]), fmaxf(acc[c][2], acc[c][3]));
        flat[s][co * 16 + pos] = fmaxf(m, 0.f) * ((kh3[co] == qh) ? 1.f : 0.f);
    }
    __syncthreads();

    // linear 320->10 for 4 samples: 40 (s,o) pairs x 4 lanes each
    if (t < 160) {
        const int g = t >> 2, qq = t & 3;
        const int ss = g / 10, o = g - ss * 10;
        float a = 0.f;
        const float* wr = Wo + o * 320;
        for (int k = qq; k < 320; k += 4) a = fmaf(flat[ss][k], wr[k], a);
        a += __shfl_xor(a, 1);
        a += __shfl_xor(a, 2);
        if (qq == 0 && b0 + ss < B) out[(size_t)(b0 + ss) * 10 + o] = a + bo[o];
    }
}

// ---------------------------------------------------------------------------
extern "C" void kernel_launch(void* const* d_in, const int* in_sizes, int n_in,
                              void* d_out, int out_size, void* d_ws, size_t ws_size,
                              hipStream_t stream)
{
    const float* x  = (const float*)d_in[0];
    const float* W1 = (const float*)d_in[1];
    const float* b1 = (const float*)d_in[2];
    const float* a1 = (const float*)d_in[3];
    const float* c1 = (const float*)d_in[4];
    const float* W2 = (const float*)d_in[5];
    const float* b2 = (const float*)d_in[6];
    const float* a2 = (const float*)d_in[7];
    const float* c2 = (const float*)d_in[8];
    const float* W3 = (const float*)d_in[9];
    const float* b3 = (const float*)d_in[10];
    const float* a3 = (const float*)d_in[11];
    const float* c3 = (const float*)d_in[12];
    const float* Wo = (const float*)d_in[13];
    const float* bo = (const float*)d_in[14];
    float* out = (float*)d_out;

    const int B = in_sizes[0] / 3072;   // 4096

    float* h1  = (float*)d_ws;                       // B*4096 f32
    float* h2  = h1 + (size_t)B * 4096;              // B*1280 f32
    float* Wp1 = h2 + (size_t)B * 1280;              // 1200
    float* Wp2 = Wp1 + 1200;                         // 8960
    float* Wp3 = Wp2 + 8960;                         // 11200
    double* dmeta = (double*)(Wp3 + 11200);          // 42 doubles (8B aligned)
    int* imeta = (int*)(dmeta + 42);                 // 56 ints
    int* qh2 = imeta + 56;                           // B ints
    int* qh3 = qh2 + B;

    setup_kernel<<<1, 256, 0, stream>>>(W1, a1, c1, W2, a2, c2, W3, a3, c3, dmeta, imeta);
    pack_kernel<<<84, 256, 0, stream>>>(W1, W2, W3, Wp1, Wp2, Wp3);
    conv1_kernel<<<B, 256, 0, stream>>>(x, Wp1, b1, imeta, dmeta, h1, qh2);
    conv2_kernel<<<B, 256, 0, stream>>>(h1, Wp2, b2, imeta + 16, qh2, dmeta, h2, qh3);
    conv3_kernel<<<(B + 3) / 4, 256, 0, stream>>>(h2, Wp3, b3, imeta + 36, qh3, Wo, bo, out, B);
}